// Round 8
// baseline (401.689 us; speedup 1.0000x reference)
//
#include <hip/hip_runtime.h>
#include <stdint.h>

#define HT_STRIDE 262144   // 4096*64 elements per head
#define LOG2E 1.4426950408889634f

typedef __attribute__((ext_vector_type(8))) short bf16x8;
typedef __attribute__((ext_vector_type(4))) float f32x4;
typedef __attribute__((ext_vector_type(2))) float f32x2;

__device__ __forceinline__ unsigned short f2bf(float f) {
    unsigned int u = __float_as_uint(f);
    u += 0x7FFFu + ((u >> 16) & 1u);
    return (unsigned short)(u >> 16);
}

__device__ __forceinline__ float exp2_fast(float e) {
#if __has_builtin(__builtin_amdgcn_exp2f)
    return __builtin_amdgcn_exp2f(e);
#else
    return __expf(e * 0.6931471805599453f);   // expf(ln2*x) == 2^x
#endif
}

// ---------------------------------------------------------------------------
// Kernel 1 (heterogeneous fusion, 1024 blocks x 256 thr, bid&1 interleave):
//  even blocks: adjacency (64 MB, read once at HBM rate) -> 2 MB bitmask
//               abm[s64][c 128][li 16][g 4].
//  odd blocks : linear + prep (ht never touches global). W loads 4-deep
//               prefetched (was: consume-immediately -> ~200cyc stall/iter).
//               Emits ess/ets exp tables (max-of-products identity) + htT2.
//  Interleave -> HBM streaming and VALU compute co-resident on every CU.
// ---------------------------------------------------------------------------
__global__ void __launch_bounds__(256) k_fused(const float* __restrict__ h,
                                               const int* __restrict__ adj,
                                               const float* __restrict__ W,
                                               const float* __restrict__ aW,
                                               float* __restrict__ ess,
                                               float* __restrict__ ets,
                                               unsigned short* __restrict__ htT2,
                                               unsigned int* __restrict__ abm) {
    __shared__ unsigned int ldsT[1024];
    __shared__ float hs[8][128];
    __shared__ float ldsA[64][66];
    __shared__ float redS[4][64];
    __shared__ float redT[4][64];
    const int t = threadIdx.x;

    if ((blockIdx.x & 1) == 0) {
        // ---------------- adjmask half ----------------
        const int eid = (int)blockIdx.x >> 1;   // 0..511
        const int lane = t & 63;
        const int w = t >> 6;
        const int sb = eid >> 3;
        const int cq = eid & 7;
        for (int rr = 0; rr < 16; ++rr) {
            const int* arow = adj + (sb * 64 + w * 16 + rr) * 4096 + cq * 512;
            int v[8];
            #pragma unroll
            for (int j = 0; j < 8; ++j) v[j] = arow[j * 64 + lane];
            #pragma unroll
            for (int j = 0; j < 8; ++j) {
                unsigned long long m = __ballot(v[j] > 0);
                if (lane < 2)
                    ldsT[(2 * j + lane) * 64 + rr * 4 + w] = (unsigned int)(m >> (lane * 32));
            }
        }
        __syncthreads();
        ((uint4*)(abm + (sb * 128 + cq * 16) * 64))[t] = ((uint4*)ldsT)[t];
    } else {
        // ---------------- linear + prep half ----------------
        const int bid2 = (int)blockIdx.x >> 1;  // 0..511
        const int n0 = bid2 * 8;            // P-row base (rows of h @ W)
        const int p0 = bid2 * 64;           // flat node base = hd*4096 + m0
        const int hd = p0 >> 12;
        const int m0 = p0 & 4095;

        // stage 8 h-rows (4 KB), coalesced
        {
            float4 v = ((const float4*)(h + n0 * 128))[t];
            int e = t * 4;
            int r = e >> 7, f = e & 127;
            hs[r][f + 0] = v.x; hs[r][f + 1] = v.y;
            hs[r][f + 2] = v.z; hs[r][f + 3] = v.w;
        }
        __syncthreads();

        // 8x512 P-tile: thread t owns cols (2t, 2t+1) for all 8 rows.
        // W loads 4-deep prefetched: issue chunk fb+1 before computing fb.
        float acc0[8], acc1[8];
        #pragma unroll
        for (int r = 0; r < 8; ++r) { acc0[r] = 0.f; acc1[r] = 0.f; }
        const float2* Wf = (const float2*)W;
        float2 wpb[4];
        #pragma unroll
        for (int j = 0; j < 4; ++j) wpb[j] = Wf[j * 256 + t];
        for (int fb = 0; fb < 32; ++fb) {
            const int fn = ((fb + 1) & 31) * 4;      // fb=31 wraps (harmless)
            float2 wn[4];
            #pragma unroll
            for (int j = 0; j < 4; ++j) wn[j] = Wf[(fn + j) * 256 + t];
            #pragma unroll
            for (int j = 0; j < 4; ++j) {
                const int f = fb * 4 + j;
                #pragma unroll
                for (int r = 0; r < 8; ++r) {
                    float hv = hs[r][f];
                    acc0[r] = fmaf(hv, wpb[j].x, acc0[r]);
                    acc1[r] = fmaf(hv, wpb[j].y, acc1[r]);
                }
            }
            #pragma unroll
            for (int j = 0; j < 4; ++j) wpb[j] = wn[j];
        }
        // scatter into node-major tile: node = 8r + (2t)>>6, o = (2t)&63
        {
            const int ns = t >> 5;
            const int o = (2 * t) & 63;
            #pragma unroll
            for (int r = 0; r < 8; ++r) {
                *(float2*)&ldsA[r * 8 + ns][o] = make_float2(acc0[r], acc1[r]);
            }
        }
        __syncthreads();

        // src/tgt projections
        {
            const int r = t & 63, og = t >> 6;
            float sdot = 0.f, gdot = 0.f;
            #pragma unroll
            for (int k = 0; k < 16; ++k) {
                int o = og * 16 + k;
                float hv = ldsA[r][o];
                sdot = fmaf(hv, aW[hd * 128 + o], sdot);
                gdot = fmaf(hv, aW[hd * 128 + 64 + o], gdot);
            }
            redS[og][r] = sdot; redT[og][r] = gdot;
        }
        __syncthreads();
        if (t < 64) {
            float sp = (redS[0][t] + redS[1][t] + redS[2][t] + redS[3][t]) * LOG2E;
            ess[hd * 8192 + m0 + t]        = exp2_fast(sp);
            ess[hd * 8192 + 4096 + m0 + t] = exp2_fast(0.2f * sp);
        } else if (t < 128) {
            int r = t - 64;
            float tv = (redT[0][r] + redT[1][r] + redT[2][r] + redT[3][r]) * LOG2E;
            ets[hd * 8192 + m0 + r]        = exp2_fast(tv);
            ets[hd * 8192 + 4096 + m0 + r] = exp2_fast(0.2f * tv);
        }

        // bf16 k-tiled transpose out (reads ldsA, stable since last barrier)
        unsigned short* d = htT2 + (hd * 128 + (m0 >> 5)) * 2048;
        #pragma unroll
        for (int i = 0; i < 16; ++i) {
            int id = t + 256 * i;
            int mi = id & 31, o = (id >> 5) & 63, ct = id >> 11;
            d[ct * 2048 + o * 32 + mi] = f2bf(ldsA[mi + 32 * ct][o]);
        }
    }
}

// ---------------------------------------------------------------------------
// Kernel 2 v10: v8 inner loop at full occupancy.
// grid 1024 x 512 thr: block = (head = bid&7 -> XCD-pinned, s32 = bid>>3).
// 8 waves = 8 k-EIGHTHS (16 c-iters each); wave: 32 rows (2 g2) x 16 c.
// Same per-wave register state as v8 (VGPR 52) -> fits 8 waves/SIMD:
// 4 blocks/CU x 8 waves = 32 waves/CU = 100% static occupancy (v8: 50%).
// Stall pool (~25 us, constant since R3) is latency-type -> 2x wave
// coverage should halve it. Combine: 3-stage LDS tree (8->4->2->1).
// LDS: 32 KB et/et2 tables -> 36.9 KB combine union. pd via ones-A MFMA.
// ---------------------------------------------------------------------------
__global__ void __launch_bounds__(512, 8) k_attn(const unsigned int* __restrict__ abm,
                                                 const unsigned short* __restrict__ htT2,
                                                 const float* __restrict__ ess,
                                                 const float* __restrict__ ets,
                                                 float* __restrict__ out) {
    __shared__ __align__(16) float smem[9216];    // 36864 B: tables -> comb union

    const int t = threadIdx.x;
    const int kq = t >> 6;                   // 0..7 (k-eighth)
    const int lane = t & 63;
    const int li = lane & 15;
    const int quad = lane >> 4;
    const int head = blockIdx.x & 7;
    const int s32 = blockIdx.x >> 3;         // 0..127
    const int s64 = s32 >> 1, half = s32 & 1;
    const int i0 = s32 * 32;

    // phase 0: stage SoA et/et2 head-slice (32 KB, contiguous copy)
    {
        const float4* esrc = (const float4*)(ets + head * 8192);
        float4* edst = (float4*)smem;
        #pragma unroll
        for (int i = 0; i < 4; ++i) edst[t + 512 * i] = esrc[t + 512 * i];
    }

    // per-row constants (table lookups, no exp)
    f32x2 esv[2], es2v[2];
    #pragma unroll
    for (int g2 = 0; g2 < 2; ++g2) {
        float e1 = ess[head * 8192 + i0 + 16 * g2 + li];
        float e2 = ess[head * 8192 + 4096 + i0 + 16 * g2 + li];
        esv[g2]  = (f32x2){e1, e1};
        es2v[g2] = (f32x2){e2, e2};
    }

    f32x4 acc[8];
    #pragma unroll
    for (int i = 0; i < 8; ++i) acc[i] = (f32x4){0.f, 0.f, 0.f, 0.f};
    f32x4 apd[2];
    apd[0] = (f32x4){0.f, 0.f, 0.f, 0.f};
    apd[1] = (f32x4){0.f, 0.f, 0.f, 0.f};

    const uint4 onesw = {0x3F803F80u, 0x3F803F80u, 0x3F803F80u, 0x3F803F80u};
    const bf16x8 aones = __builtin_bit_cast(bf16x8, onesw);

    const uint4* ap = (const uint4*)(htT2 + head * HT_STRIDE) + (li * 4 + quad);
    const unsigned int* bmp = abm + s64 * 8192 + half * 2 + li * 4;

    __syncthreads();

    const int c0 = kq * 16;
    #pragma unroll 1
    for (int ci = 0; ci < 16; ++ci) {
        const int c = c0 + ci;
        uint4 av0 = ap[c * 256 + 0];
        uint4 av1 = ap[c * 256 + 64];
        uint4 av2 = ap[c * 256 + 128];
        uint4 av3 = ap[c * 256 + 192];
        uint2 bw = *(const uint2*)(bmp + c * 64);     // L2-resident bitwords

        // SoA et/et2 for this quad's 8 cols (LDS broadcast, pk-adjacent)
        const float4* etp  = (const float4*)(smem + c * 32 + quad * 8);
        const float4* et2p = (const float4*)(smem + 4096 + c * 32 + quad * 8);
        float4 ta = etp[0],  tb = etp[1];
        float4 ua = et2p[0], ub = et2p[1];
        const f32x2 etq[4]  = {(f32x2){ta.x, ta.y}, (f32x2){ta.z, ta.w},
                               (f32x2){tb.x, tb.y}, (f32x2){tb.z, tb.w}};
        const f32x2 et2q[4] = {(f32x2){ua.x, ua.y}, (f32x2){ua.z, ua.w},
                               (f32x2){ub.x, ub.y}, (f32x2){ub.z, ub.w}};

        const unsigned int wb[2] = {bw.x, bw.y};
        #pragma unroll
        for (int g2 = 0; g2 < 2; ++g2) {
            const unsigned int wq = wb[g2] >> (quad * 8);
            unsigned int pk[4];
            #pragma unroll
            for (int m = 0; m < 4; ++m) {
                f32x2 p1 = etq[m] * esv[g2];          // v_pk_mul_f32
                f32x2 p2 = et2q[m] * es2v[g2];        // v_pk_mul_f32
                float w0 = fmaxf(p1[0], p2[0]);
                float w1 = fmaxf(p1[1], p2[1]);
                unsigned int pkm;
                asm("v_cvt_pk_bf16_f32 %0, %1, %2" : "=v"(pkm) : "v"(w0), "v"(w1));
                const int j0 = 2 * m, j1 = 2 * m + 1;
                const unsigned int lo = (unsigned int)((int)(wq << (31 - j0)) >> 31);
                const unsigned int hi = (unsigned int)((int)(wq << (31 - j1)) >> 31);
                pk[m] = pkm & ((lo & 0x0000FFFFu) | (hi & 0xFFFF0000u));
            }
            uint4 bv; bv.x = pk[0]; bv.y = pk[1]; bv.z = pk[2]; bv.w = pk[3];
            bf16x8 bfrag = __builtin_bit_cast(bf16x8, bv);
            apd[g2] = __builtin_amdgcn_mfma_f32_16x16x32_bf16(aones, bfrag, apd[g2], 0, 0, 0);
            acc[g2 * 4 + 0] = __builtin_amdgcn_mfma_f32_16x16x32_bf16(__builtin_bit_cast(bf16x8, av0), bfrag, acc[g2 * 4 + 0], 0, 0, 0);
            acc[g2 * 4 + 1] = __builtin_amdgcn_mfma_f32_16x16x32_bf16(__builtin_bit_cast(bf16x8, av1), bfrag, acc[g2 * 4 + 1], 0, 0, 0);
            acc[g2 * 4 + 2] = __builtin_amdgcn_mfma_f32_16x16x32_bf16(__builtin_bit_cast(bf16x8, av2), bfrag, acc[g2 * 4 + 2], 0, 0, 0);
            acc[g2 * 4 + 3] = __builtin_amdgcn_mfma_f32_16x16x32_bf16(__builtin_bit_cast(bf16x8, av3), bfrag, acc[g2 * 4 + 3], 0, 0, 0);
        }
    }

    // ---- phase 3: 3-stage tree combine (8 -> 4 -> 2 -> 1), then store ----
    float pdv[2] = {apd[0][0], apd[1][0]};
    __syncthreads();             // all waves done with et tables before overwrite

    // stage 1: waves 4..7 write slots 0..3; waves 0..3 add
    if (kq >= 4) {
        float* cb = smem + ((kq - 4) * 64 + lane) * 36;
        #pragma unroll
        for (int i = 0; i < 8; ++i) ((f32x4*)cb)[i] = acc[i];
        cb[32] = pdv[0]; cb[33] = pdv[1];
    }
    __syncthreads();
    if (kq < 4) {
        const float* cb = smem + (kq * 64 + lane) * 36;
        #pragma unroll
        for (int i = 0; i < 8; ++i) acc[i] += ((const f32x4*)cb)[i];
        pdv[0] += cb[32]; pdv[1] += cb[33];
    }
    __syncthreads();
    // stage 2: waves 2..3 write slots 0..1; waves 0..1 add
    if (kq == 2 || kq == 3) {
        float* cb = smem + ((kq - 2) * 64 + lane) * 36;
        #pragma unroll
        for (int i = 0; i < 8; ++i) ((f32x4*)cb)[i] = acc[i];
        cb[32] = pdv[0]; cb[33] = pdv[1];
    }
    __syncthreads();
    if (kq < 2) {
        const float* cb = smem + (kq * 64 + lane) * 36;
        #pragma unroll
        for (int i = 0; i < 8; ++i) acc[i] += ((const f32x4*)cb)[i];
        pdv[0] += cb[32]; pdv[1] += cb[33];
    }
    __syncthreads();
    // stage 3: wave 1 writes slot 0; wave 0 adds + stores
    if (kq == 1) {
        float* cb = smem + lane * 36;
        #pragma unroll
        for (int i = 0; i < 8; ++i) ((f32x4*)cb)[i] = acc[i];
        cb[32] = pdv[0]; cb[33] = pdv[1];
    }
    __syncthreads();
    if (kq == 0) {
        const float* cb = smem + lane * 36;
        #pragma unroll
        for (int i = 0; i < 8; ++i) acc[i] += ((const f32x4*)cb)[i];
        pdv[0] += cb[32]; pdv[1] += cb[33];
        #pragma unroll
        for (int g2 = 0; g2 < 2; ++g2) {
            const float rd = 1.0f / pdv[g2];  // ones-MFMA already summed k+quads
            float4* op = (float4*)(out + head * HT_STRIDE + (i0 + 16 * g2 + li) * 64);
            #pragma unroll
            for (int f = 0; f < 4; ++f) {
                f32x4 a = acc[g2 * 4 + f];
                op[f * 4 + quad] = make_float4(a[0] * rd, a[1] * rd, a[2] * rd, a[3] * rd);
            }
        }
    }
}

extern "C" void kernel_launch(void* const* d_in, const int* in_sizes, int n_in,
                              void* d_out, int out_size, void* d_ws, size_t ws_size,
                              hipStream_t stream) {
    const float* h   = (const float*)d_in[0];  // (1,4096,128) f32
    const int*   adj = (const int*)d_in[1];    // (4096,4096) i32
    const float* W   = (const float*)d_in[2];  // (128,512) f32
    const float* aW  = (const float*)d_in[3];  // (8,128,1) f32
    float* out = (float*)d_out;                // (1,8,4096,64) f32

    // ws layout (6.5 MB): ess(256K) | ets(256K) | abm(2MB) | htT2(4MB)
    char* ws = (char*)d_ws;
    float* ess = (float*)(ws);
    float* ets = (float*)(ws + 262144);
    unsigned int*   abm  = (unsigned int*)(ws + 524288);
    unsigned short* htT2 = (unsigned short*)(ws + 2621440);

    hipLaunchKernelGGL(k_fused, dim3(1024), dim3(256), 0, stream,
                       h, adj, W, aW, ess, ets, htT2, abm);
    hipLaunchKernelGGL(k_attn,  dim3(1024), dim3(512), 0, stream,
                       abm, htT2, ess, ets, out);
}

// Round 9
// 211.579 us; speedup vs baseline: 1.8985x; 1.8985x over previous
//
#include <hip/hip_runtime.h>
#include <stdint.h>

#define HT_STRIDE 262144   // 4096*64 elements per head
#define LOG2E 1.4426950408889634f

typedef __attribute__((ext_vector_type(8))) short bf16x8;
typedef __attribute__((ext_vector_type(4))) float f32x4;
typedef __attribute__((ext_vector_type(2))) float f32x2;

__device__ __forceinline__ unsigned short f2bf(float f) {
    unsigned int u = __float_as_uint(f);
    u += 0x7FFFu + ((u >> 16) & 1u);
    return (unsigned short)(u >> 16);
}

__device__ __forceinline__ float exp2_fast(float e) {
#if __has_builtin(__builtin_amdgcn_exp2f)
    return __builtin_amdgcn_exp2f(e);
#else
    return __expf(e * 0.6931471805599453f);   // expf(ln2*x) == 2^x
#endif
}

// ---------------------------------------------------------------------------
// Kernel 1 (heterogeneous fusion, 1024 blocks x 256 thr, bid&1 interleave):
//  even blocks: adjacency (64 MB, read once at HBM rate) -> 2 MB bitmask
//               abm[s64][c 128][li 16][g 4].
//  odd blocks : linear + prep (ht never touches global). W loads 4-deep
//               prefetched. Emits ess/ets exp tables (max-of-products
//               identity) + bf16 k-tiled htT2.
// ---------------------------------------------------------------------------
__global__ void __launch_bounds__(256) k_fused(const float* __restrict__ h,
                                               const int* __restrict__ adj,
                                               const float* __restrict__ W,
                                               const float* __restrict__ aW,
                                               float* __restrict__ ess,
                                               float* __restrict__ ets,
                                               unsigned short* __restrict__ htT2,
                                               unsigned int* __restrict__ abm) {
    __shared__ unsigned int ldsT[1024];
    __shared__ float hs[8][128];
    __shared__ float ldsA[64][66];
    __shared__ float redS[4][64];
    __shared__ float redT[4][64];
    const int t = threadIdx.x;

    if ((blockIdx.x & 1) == 0) {
        // ---------------- adjmask half ----------------
        const int eid = (int)blockIdx.x >> 1;   // 0..511
        const int lane = t & 63;
        const int w = t >> 6;
        const int sb = eid >> 3;
        const int cq = eid & 7;
        for (int rr = 0; rr < 16; ++rr) {
            const int* arow = adj + (sb * 64 + w * 16 + rr) * 4096 + cq * 512;
            int v[8];
            #pragma unroll
            for (int j = 0; j < 8; ++j) v[j] = arow[j * 64 + lane];
            #pragma unroll
            for (int j = 0; j < 8; ++j) {
                unsigned long long m = __ballot(v[j] > 0);
                if (lane < 2)
                    ldsT[(2 * j + lane) * 64 + rr * 4 + w] = (unsigned int)(m >> (lane * 32));
            }
        }
        __syncthreads();
        ((uint4*)(abm + (sb * 128 + cq * 16) * 64))[t] = ((uint4*)ldsT)[t];
    } else {
        // ---------------- linear + prep half ----------------
        const int bid2 = (int)blockIdx.x >> 1;  // 0..511
        const int n0 = bid2 * 8;            // P-row base (rows of h @ W)
        const int p0 = bid2 * 64;           // flat node base = hd*4096 + m0
        const int hd = p0 >> 12;
        const int m0 = p0 & 4095;

        // stage 8 h-rows (4 KB), coalesced
        {
            float4 v = ((const float4*)(h + n0 * 128))[t];
            int e = t * 4;
            int r = e >> 7, f = e & 127;
            hs[r][f + 0] = v.x; hs[r][f + 1] = v.y;
            hs[r][f + 2] = v.z; hs[r][f + 3] = v.w;
        }
        __syncthreads();

        // 8x512 P-tile: thread t owns cols (2t, 2t+1) for all 8 rows.
        // W loads 4-deep prefetched: issue chunk fb+1 before computing fb.
        float acc0[8], acc1[8];
        #pragma unroll
        for (int r = 0; r < 8; ++r) { acc0[r] = 0.f; acc1[r] = 0.f; }
        const float2* Wf = (const float2*)W;
        float2 wpb[4];
        #pragma unroll
        for (int j = 0; j < 4; ++j) wpb[j] = Wf[j * 256 + t];
        for (int fb = 0; fb < 32; ++fb) {
            const int fn = ((fb + 1) & 31) * 4;      // fb=31 wraps (harmless)
            float2 wn[4];
            #pragma unroll
            for (int j = 0; j < 4; ++j) wn[j] = Wf[(fn + j) * 256 + t];
            #pragma unroll
            for (int j = 0; j < 4; ++j) {
                const int f = fb * 4 + j;
                #pragma unroll
                for (int r = 0; r < 8; ++r) {
                    float hv = hs[r][f];
                    acc0[r] = fmaf(hv, wpb[j].x, acc0[r]);
                    acc1[r] = fmaf(hv, wpb[j].y, acc1[r]);
                }
            }
            #pragma unroll
            for (int j = 0; j < 4; ++j) wpb[j] = wn[j];
        }
        // scatter into node-major tile: node = 8r + (2t)>>6, o = (2t)&63
        {
            const int ns = t >> 5;
            const int o = (2 * t) & 63;
            #pragma unroll
            for (int r = 0; r < 8; ++r) {
                *(float2*)&ldsA[r * 8 + ns][o] = make_float2(acc0[r], acc1[r]);
            }
        }
        __syncthreads();

        // src/tgt projections
        {
            const int r = t & 63, og = t >> 6;
            float sdot = 0.f, gdot = 0.f;
            #pragma unroll
            for (int k = 0; k < 16; ++k) {
                int o = og * 16 + k;
                float hv = ldsA[r][o];
                sdot = fmaf(hv, aW[hd * 128 + o], sdot);
                gdot = fmaf(hv, aW[hd * 128 + 64 + o], gdot);
            }
            redS[og][r] = sdot; redT[og][r] = gdot;
        }
        __syncthreads();
        if (t < 64) {
            float sp = (redS[0][t] + redS[1][t] + redS[2][t] + redS[3][t]) * LOG2E;
            ess[hd * 8192 + m0 + t]        = exp2_fast(sp);
            ess[hd * 8192 + 4096 + m0 + t] = exp2_fast(0.2f * sp);
        } else if (t < 128) {
            int r = t - 64;
            float tv = (redT[0][r] + redT[1][r] + redT[2][r] + redT[3][r]) * LOG2E;
            ets[hd * 8192 + m0 + r]        = exp2_fast(tv);
            ets[hd * 8192 + 4096 + m0 + r] = exp2_fast(0.2f * tv);
        }

        // bf16 k-tiled transpose out (reads ldsA, stable since last barrier)
        unsigned short* d = htT2 + (hd * 128 + (m0 >> 5)) * 2048;
        #pragma unroll
        for (int i = 0; i < 16; ++i) {
            int id = t + 256 * i;
            int mi = id & 31, o = (id >> 5) & 63, ct = id >> 11;
            d[ct * 2048 + o * 32 + mi] = f2bf(ldsA[mi + 32 * ct][o]);
        }
    }
}

// ---------------------------------------------------------------------------
// Kernel 2 v11: 64-row x 8-wave — halved A-stream AT R6 occupancy.
// grid 512 x 512 thr: block = (head = bid&7 -> XCD-pinned, s64 = bid>>3).
// 8 waves = 8 k-eighths (16 c-iters); wave: 64 rows (4 g2-groups).
// The untested matrix cell from R3-R8: per-XCD L2 A-traffic 64 -> 32 MB
// (each 4KB A-load batch feeds 64 rows, R7) WHILE keeping 4 waves/SIMD
// (2 blocks/CU x 8 waves, R6). Per-wave reg state == R7's proven VGPR-80
// kernel; __launch_bounds__(512,4) caps at 128 (R8 spill guard).
// LDS: 32 KB et/et2 tables -> 68 KB 3-stage combine union -> 2 blocks/CU.
// pd via ones-A MFMA. Mask via bfe/bfi (vcc-free).
// ---------------------------------------------------------------------------
__global__ void __launch_bounds__(512, 4) k_attn(const unsigned int* __restrict__ abm,
                                                 const unsigned short* __restrict__ htT2,
                                                 const float* __restrict__ ess,
                                                 const float* __restrict__ ets,
                                                 float* __restrict__ out) {
    __shared__ __align__(16) float smem[17408];   // 69632 B: tables -> comb union

    const int t = threadIdx.x;
    const int kq = t >> 6;                   // 0..7 (k-eighth)
    const int lane = t & 63;
    const int li = lane & 15;
    const int quad = lane >> 4;
    const int head = blockIdx.x & 7;
    const int s64 = blockIdx.x >> 3;         // 0..63
    const int i0 = s64 * 64;

    // phase 0: stage SoA et/et2 head-slice (32 KB, contiguous copy)
    {
        const float4* esrc = (const float4*)(ets + head * 8192);
        float4* edst = (float4*)smem;
        #pragma unroll
        for (int i = 0; i < 4; ++i) edst[t + 512 * i] = esrc[t + 512 * i];
    }

    // per-row constants (table lookups, no exp): 4 row-groups
    f32x2 esv[4], es2v[4];
    #pragma unroll
    for (int g2 = 0; g2 < 4; ++g2) {
        float e1 = ess[head * 8192 + i0 + 16 * g2 + li];
        float e2 = ess[head * 8192 + 4096 + i0 + 16 * g2 + li];
        esv[g2]  = (f32x2){e1, e1};
        es2v[g2] = (f32x2){e2, e2};
    }

    f32x4 acc[16];
    #pragma unroll
    for (int i = 0; i < 16; ++i) acc[i] = (f32x4){0.f, 0.f, 0.f, 0.f};
    f32x4 apd[4];
    #pragma unroll
    for (int g2 = 0; g2 < 4; ++g2) apd[g2] = (f32x4){0.f, 0.f, 0.f, 0.f};

    const uint4 onesw = {0x3F803F80u, 0x3F803F80u, 0x3F803F80u, 0x3F803F80u};
    const bf16x8 aones = __builtin_bit_cast(bf16x8, onesw);
    const unsigned int lohalf = 0x0000FFFFu;

    const uint4* ap  = (const uint4*)(htT2 + head * HT_STRIDE) + (li * 4 + quad);
    const uint4* bmp = (const uint4*)(abm + s64 * 8192 + li * 4);

    __syncthreads();

    const int c0 = kq * 16;
    #pragma unroll 1
    for (int ci = 0; ci < 16; ++ci) {
        const int c = c0 + ci;
        uint4 av0 = ap[c * 256 + 0];
        uint4 av1 = ap[c * 256 + 64];
        uint4 av2 = ap[c * 256 + 128];
        uint4 av3 = ap[c * 256 + 192];
        uint4 bw = bmp[c * 16];               // g=0..3 bitwords, coalesced

        // SoA et/et2 for this quad's 8 cols (LDS broadcast, pk-adjacent)
        const float4* etp  = (const float4*)(smem + c * 32 + quad * 8);
        const float4* et2p = (const float4*)(smem + 4096 + c * 32 + quad * 8);
        float4 ta = etp[0],  tb = etp[1];
        float4 ua = et2p[0], ub = et2p[1];
        const f32x2 etq[4]  = {(f32x2){ta.x, ta.y}, (f32x2){ta.z, ta.w},
                               (f32x2){tb.x, tb.y}, (f32x2){tb.z, tb.w}};
        const f32x2 et2q[4] = {(f32x2){ua.x, ua.y}, (f32x2){ua.z, ua.w},
                               (f32x2){ub.x, ub.y}, (f32x2){ub.z, ub.w}};

        const unsigned int wb[4] = {bw.x, bw.y, bw.z, bw.w};
        #pragma unroll
        for (int g2 = 0; g2 < 4; ++g2) {
            const unsigned int wq = wb[g2] >> (quad * 8);
            unsigned int pk[4];
            #pragma unroll
            for (int m = 0; m < 4; ++m) {
                f32x2 p1 = etq[m] * esv[g2];          // v_pk_mul_f32
                f32x2 p2 = et2q[m] * es2v[g2];        // v_pk_mul_f32
                float w0 = fmaxf(p1[0], p2[0]);
                float w1 = fmaxf(p1[1], p2[1]);
                unsigned int pkm;
                asm("v_cvt_pk_bf16_f32 %0, %1, %2" : "=v"(pkm) : "v"(w0), "v"(w1));
                unsigned int lo, hi, msk;
                asm("v_bfe_i32 %0, %1, %2, 1" : "=v"(lo) : "v"(wq), "n"(2 * m));
                asm("v_bfe_i32 %0, %1, %2, 1" : "=v"(hi) : "v"(wq), "n"(2 * m + 1));
                asm("v_bfi_b32 %0, %1, %2, %3" : "=v"(msk) : "v"(lohalf), "v"(lo), "v"(hi));
                pk[m] = pkm & msk;
            }
            uint4 bv; bv.x = pk[0]; bv.y = pk[1]; bv.z = pk[2]; bv.w = pk[3];
            bf16x8 bfrag = __builtin_bit_cast(bf16x8, bv);
            apd[g2] = __builtin_amdgcn_mfma_f32_16x16x32_bf16(aones, bfrag, apd[g2], 0, 0, 0);
            acc[g2 * 4 + 0] = __builtin_amdgcn_mfma_f32_16x16x32_bf16(__builtin_bit_cast(bf16x8, av0), bfrag, acc[g2 * 4 + 0], 0, 0, 0);
            acc[g2 * 4 + 1] = __builtin_amdgcn_mfma_f32_16x16x32_bf16(__builtin_bit_cast(bf16x8, av1), bfrag, acc[g2 * 4 + 1], 0, 0, 0);
            acc[g2 * 4 + 2] = __builtin_amdgcn_mfma_f32_16x16x32_bf16(__builtin_bit_cast(bf16x8, av2), bfrag, acc[g2 * 4 + 2], 0, 0, 0);
            acc[g2 * 4 + 3] = __builtin_amdgcn_mfma_f32_16x16x32_bf16(__builtin_bit_cast(bf16x8, av3), bfrag, acc[g2 * 4 + 3], 0, 0, 0);
        }
    }

    // ---- phase 3: 3-stage tree combine (8 -> 4 -> 2 -> 1), then store ----
    float pdv[4] = {apd[0][0], apd[1][0], apd[2][0], apd[3][0]};
    __syncthreads();             // all waves done with et tables before overwrite

    // stage 1: waves 4..7 write slots 0..3; waves 0..3 add
    if (kq >= 4) {
        float* cb = smem + ((kq - 4) * 64 + lane) * 68;
        #pragma unroll
        for (int i = 0; i < 16; ++i) ((f32x4*)cb)[i] = acc[i];
        #pragma unroll
        for (int g2 = 0; g2 < 4; ++g2) cb[64 + g2] = pdv[g2];
    }
    __syncthreads();
    if (kq < 4) {
        const float* cb = smem + (kq * 64 + lane) * 68;
        #pragma unroll
        for (int i = 0; i < 16; ++i) acc[i] += ((const f32x4*)cb)[i];
        #pragma unroll
        for (int g2 = 0; g2 < 4; ++g2) pdv[g2] += cb[64 + g2];
    }
    __syncthreads();
    // stage 2: waves 2..3 write slots 0..1; waves 0..1 add
    if (kq == 2 || kq == 3) {
        float* cb = smem + ((kq - 2) * 64 + lane) * 68;
        #pragma unroll
        for (int i = 0; i < 16; ++i) ((f32x4*)cb)[i] = acc[i];
        #pragma unroll
        for (int g2 = 0; g2 < 4; ++g2) cb[64 + g2] = pdv[g2];
    }
    __syncthreads();
    if (kq < 2) {
        const float* cb = smem + (kq * 64 + lane) * 68;
        #pragma unroll
        for (int i = 0; i < 16; ++i) acc[i] += ((const f32x4*)cb)[i];
        #pragma unroll
        for (int g2 = 0; g2 < 4; ++g2) pdv[g2] += cb[64 + g2];
    }
    __syncthreads();
    // stage 3: wave 1 writes slot 0; wave 0 adds + stores
    if (kq == 1) {
        float* cb = smem + lane * 68;
        #pragma unroll
        for (int i = 0; i < 16; ++i) ((f32x4*)cb)[i] = acc[i];
        #pragma unroll
        for (int g2 = 0; g2 < 4; ++g2) cb[64 + g2] = pdv[g2];
    }
    __syncthreads();
    if (kq == 0) {
        const float* cb = smem + lane * 68;
        #pragma unroll
        for (int i = 0; i < 16; ++i) acc[i] += ((const f32x4*)cb)[i];
        #pragma unroll
        for (int g2 = 0; g2 < 4; ++g2) pdv[g2] += cb[64 + g2];
        #pragma unroll
        for (int g2 = 0; g2 < 4; ++g2) {
            const float rd = 1.0f / pdv[g2];  // ones-MFMA already summed k+quads
            float4* op = (float4*)(out + head * HT_STRIDE + (i0 + 16 * g2 + li) * 64);
            #pragma unroll
            for (int f = 0; f < 4; ++f) {
                f32x4 a = acc[g2 * 4 + f];
                op[f * 4 + quad] = make_float4(a[0] * rd, a[1] * rd, a[2] * rd, a[3] * rd);
            }
        }
    }
}

extern "C" void kernel_launch(void* const* d_in, const int* in_sizes, int n_in,
                              void* d_out, int out_size, void* d_ws, size_t ws_size,
                              hipStream_t stream) {
    const float* h   = (const float*)d_in[0];  // (1,4096,128) f32
    const int*   adj = (const int*)d_in[1];    // (4096,4096) i32
    const float* W   = (const float*)d_in[2];  // (128,512) f32
    const float* aW  = (const float*)d_in[3];  // (8,128,1) f32
    float* out = (float*)d_out;                // (1,8,4096,64) f32

    // ws layout (6.5 MB): ess(256K) | ets(256K) | abm(2MB) | htT2(4MB)
    char* ws = (char*)d_ws;
    float* ess = (float*)(ws);
    float* ets = (float*)(ws + 262144);
    unsigned int*   abm  = (unsigned int*)(ws + 524288);
    unsigned short* htT2 = (unsigned short*)(ws + 2621440);

    hipLaunchKernelGGL(k_fused, dim3(1024), dim3(256), 0, stream,
                       h, adj, W, aW, ess, ets, htT2, abm);
    hipLaunchKernelGGL(k_attn,  dim3(512),  dim3(512), 0, stream,
                       abm, htT2, ess, ets, out);
}

// Round 10
// 184.880 us; speedup vs baseline: 2.1727x; 1.1444x over previous
//
#include <hip/hip_runtime.h>
#include <stdint.h>

#define HT_STRIDE 262144   // 4096*64 elements per head
#define LOG2E 1.4426950408889634f

typedef __attribute__((ext_vector_type(8))) short bf16x8;
typedef __attribute__((ext_vector_type(4))) float f32x4;
typedef __attribute__((ext_vector_type(2))) float f32x2;

__device__ __forceinline__ unsigned short f2bf(float f) {
    unsigned int u = __float_as_uint(f);
    u += 0x7FFFu + ((u >> 16) & 1u);
    return (unsigned short)(u >> 16);
}

__device__ __forceinline__ float exp2_fast(float e) {
#if __has_builtin(__builtin_amdgcn_exp2f)
    return __builtin_amdgcn_exp2f(e);
#else
    return __expf(e * 0.6931471805599453f);   // expf(ln2*x) == 2^x
#endif
}

// ---------------------------------------------------------------------------
// Kernel 1 (heterogeneous fusion, 1024 blocks x 256 thr, bid&1 interleave):
//  even blocks: adjacency (64 MB, read once at HBM rate) -> 2 MB bitmask
//               abm[s64][c 128][li 16][g 4].
//  odd blocks : linear + prep (ht never touches global). W loads 4-deep
//               prefetched. Emits ess/ets exp tables (max-of-products
//               identity) + bf16 k-tiled htT2.
// ---------------------------------------------------------------------------
__global__ void __launch_bounds__(256) k_fused(const float* __restrict__ h,
                                               const int* __restrict__ adj,
                                               const float* __restrict__ W,
                                               const float* __restrict__ aW,
                                               float* __restrict__ ess,
                                               float* __restrict__ ets,
                                               unsigned short* __restrict__ htT2,
                                               unsigned int* __restrict__ abm) {
    __shared__ unsigned int ldsT[1024];
    __shared__ float hs[8][128];
    __shared__ float ldsA[64][66];
    __shared__ float redS[4][64];
    __shared__ float redT[4][64];
    const int t = threadIdx.x;

    if ((blockIdx.x & 1) == 0) {
        // ---------------- adjmask half ----------------
        const int eid = (int)blockIdx.x >> 1;   // 0..511
        const int lane = t & 63;
        const int w = t >> 6;
        const int sb = eid >> 3;
        const int cq = eid & 7;
        for (int rr = 0; rr < 16; ++rr) {
            const int* arow = adj + (sb * 64 + w * 16 + rr) * 4096 + cq * 512;
            int v[8];
            #pragma unroll
            for (int j = 0; j < 8; ++j) v[j] = arow[j * 64 + lane];
            #pragma unroll
            for (int j = 0; j < 8; ++j) {
                unsigned long long m = __ballot(v[j] > 0);
                if (lane < 2)
                    ldsT[(2 * j + lane) * 64 + rr * 4 + w] = (unsigned int)(m >> (lane * 32));
            }
        }
        __syncthreads();
        ((uint4*)(abm + (sb * 128 + cq * 16) * 64))[t] = ((uint4*)ldsT)[t];
    } else {
        // ---------------- linear + prep half ----------------
        const int bid2 = (int)blockIdx.x >> 1;  // 0..511
        const int n0 = bid2 * 8;            // P-row base (rows of h @ W)
        const int p0 = bid2 * 64;           // flat node base = hd*4096 + m0
        const int hd = p0 >> 12;
        const int m0 = p0 & 4095;

        // stage 8 h-rows (4 KB), coalesced
        {
            float4 v = ((const float4*)(h + n0 * 128))[t];
            int e = t * 4;
            int r = e >> 7, f = e & 127;
            hs[r][f + 0] = v.x; hs[r][f + 1] = v.y;
            hs[r][f + 2] = v.z; hs[r][f + 3] = v.w;
        }
        __syncthreads();

        // 8x512 P-tile: thread t owns cols (2t, 2t+1) for all 8 rows.
        // W loads 4-deep prefetched: issue chunk fb+1 before computing fb.
        float acc0[8], acc1[8];
        #pragma unroll
        for (int r = 0; r < 8; ++r) { acc0[r] = 0.f; acc1[r] = 0.f; }
        const float2* Wf = (const float2*)W;
        float2 wpb[4];
        #pragma unroll
        for (int j = 0; j < 4; ++j) wpb[j] = Wf[j * 256 + t];
        for (int fb = 0; fb < 32; ++fb) {
            const int fn = ((fb + 1) & 31) * 4;      // fb=31 wraps (harmless)
            float2 wn[4];
            #pragma unroll
            for (int j = 0; j < 4; ++j) wn[j] = Wf[(fn + j) * 256 + t];
            #pragma unroll
            for (int j = 0; j < 4; ++j) {
                const int f = fb * 4 + j;
                #pragma unroll
                for (int r = 0; r < 8; ++r) {
                    float hv = hs[r][f];
                    acc0[r] = fmaf(hv, wpb[j].x, acc0[r]);
                    acc1[r] = fmaf(hv, wpb[j].y, acc1[r]);
                }
            }
            #pragma unroll
            for (int j = 0; j < 4; ++j) wpb[j] = wn[j];
        }
        // scatter into node-major tile: node = 8r + (2t)>>6, o = (2t)&63
        {
            const int ns = t >> 5;
            const int o = (2 * t) & 63;
            #pragma unroll
            for (int r = 0; r < 8; ++r) {
                *(float2*)&ldsA[r * 8 + ns][o] = make_float2(acc0[r], acc1[r]);
            }
        }
        __syncthreads();

        // src/tgt projections
        {
            const int r = t & 63, og = t >> 6;
            float sdot = 0.f, gdot = 0.f;
            #pragma unroll
            for (int k = 0; k < 16; ++k) {
                int o = og * 16 + k;
                float hv = ldsA[r][o];
                sdot = fmaf(hv, aW[hd * 128 + o], sdot);
                gdot = fmaf(hv, aW[hd * 128 + 64 + o], gdot);
            }
            redS[og][r] = sdot; redT[og][r] = gdot;
        }
        __syncthreads();
        if (t < 64) {
            float sp = (redS[0][t] + redS[1][t] + redS[2][t] + redS[3][t]) * LOG2E;
            ess[hd * 8192 + m0 + t]        = exp2_fast(sp);
            ess[hd * 8192 + 4096 + m0 + t] = exp2_fast(0.2f * sp);
        } else if (t < 128) {
            int r = t - 64;
            float tv = (redT[0][r] + redT[1][r] + redT[2][r] + redT[3][r]) * LOG2E;
            ets[hd * 8192 + m0 + r]        = exp2_fast(tv);
            ets[hd * 8192 + 4096 + m0 + r] = exp2_fast(0.2f * tv);
        }

        // bf16 k-tiled transpose out (reads ldsA, stable since last barrier)
        unsigned short* d = htT2 + (hd * 128 + (m0 >> 5)) * 2048;
        #pragma unroll
        for (int i = 0; i < 16; ++i) {
            int id = t + 256 * i;
            int mi = id & 31, o = (id >> 5) & 63, ct = id >> 11;
            d[ct * 2048 + o * 32 + mi] = f2bf(ldsA[mi + 32 * ct][o]);
        }
    }
}

// ---------------------------------------------------------------------------
// Kernel 2 v12: v8 inner loop, 16-row waves, NO register cap.
// grid 1024 x 512 thr: block = (head = bid&7 -> XCD-pinned, s32 = bid>>3).
// 8 waves = (row-half rh = wv>>2) x (k-quarter kq = wv&3).
// Per wave: 16 rows (1 g2), 32 c-iters — acc shrinks to 16+4 = 20 unified
// regs; total footprint ~70 (v8: 92) -> 3-4 blocks/CU = 24-32 waves/CU
// (75-100%) WITHOUT any __launch_bounds__ min-waves cap (R8/R9 lesson:
// the cap covers arch+acc combined; capping below demand spills the
// accumulators to scratch -> 100x WRITE_SIZE). The second row-half's
// A-tile reads hit L1/L2 (same CU, same c-sequence).
// LDS: 32 KB et/et2 tables -> 30.7 KB combine union (6 slots x 64 x 20).
// pd via ones-A MFMA. Bitwords direct from global (L2-resident).
// ---------------------------------------------------------------------------
__global__ void __launch_bounds__(512) k_attn(const unsigned int* __restrict__ abm,
                                              const unsigned short* __restrict__ htT2,
                                              const float* __restrict__ ess,
                                              const float* __restrict__ ets,
                                              float* __restrict__ out) {
    __shared__ __align__(16) float smem[8192];    // 32 KB: tables -> comb union

    const int t = threadIdx.x;
    const int wv = t >> 6;                   // 0..7
    const int rh = wv >> 2;                  // row-half (== g2)
    const int kq = wv & 3;                   // k-quarter
    const int lane = t & 63;
    const int li = lane & 15;
    const int quad = lane >> 4;
    const int head = blockIdx.x & 7;
    const int s32 = blockIdx.x >> 3;         // 0..127
    const int s64 = s32 >> 1, half = s32 & 1;
    const int i0 = s32 * 32;

    // phase 0: stage SoA et/et2 head-slice (32 KB, contiguous copy)
    {
        const float4* esrc = (const float4*)(ets + head * 8192);
        float4* edst = (float4*)smem;
        #pragma unroll
        for (int i = 0; i < 4; ++i) edst[t + 512 * i] = esrc[t + 512 * i];
    }

    // per-row constants (table lookups, no exp): this wave's 16 rows
    const float e1 = ess[head * 8192 + i0 + 16 * rh + li];
    const float e2 = ess[head * 8192 + 4096 + i0 + 16 * rh + li];
    const f32x2 esv  = (f32x2){e1, e1};
    const f32x2 es2v = (f32x2){e2, e2};

    f32x4 acc[4];
    #pragma unroll
    for (int i = 0; i < 4; ++i) acc[i] = (f32x4){0.f, 0.f, 0.f, 0.f};
    f32x4 apd = (f32x4){0.f, 0.f, 0.f, 0.f};

    const uint4 onesw = {0x3F803F80u, 0x3F803F80u, 0x3F803F80u, 0x3F803F80u};
    const bf16x8 aones = __builtin_bit_cast(bf16x8, onesw);

    const uint4* ap = (const uint4*)(htT2 + head * HT_STRIDE) + (li * 4 + quad);
    // bitword for this wave's 16 rows: g = half*2 + rh
    const unsigned int* bmp = abm + s64 * 8192 + li * 4 + half * 2 + rh;

    __syncthreads();

    const int c0 = kq * 32;
    #pragma unroll 1
    for (int ci = 0; ci < 32; ++ci) {
        const int c = c0 + ci;
        uint4 av0 = ap[c * 256 + 0];
        uint4 av1 = ap[c * 256 + 64];
        uint4 av2 = ap[c * 256 + 128];
        uint4 av3 = ap[c * 256 + 192];
        const unsigned int bw = bmp[c * 64];          // L2-resident bitword

        // SoA et/et2 for this quad's 8 cols (LDS broadcast, pk-adjacent)
        const float4* etp  = (const float4*)(smem + c * 32 + quad * 8);
        const float4* et2p = (const float4*)(smem + 4096 + c * 32 + quad * 8);
        float4 ta = etp[0],  tb = etp[1];
        float4 ua = et2p[0], ub = et2p[1];
        const f32x2 etq[4]  = {(f32x2){ta.x, ta.y}, (f32x2){ta.z, ta.w},
                               (f32x2){tb.x, tb.y}, (f32x2){tb.z, tb.w}};
        const f32x2 et2q[4] = {(f32x2){ua.x, ua.y}, (f32x2){ua.z, ua.w},
                               (f32x2){ub.x, ub.y}, (f32x2){ub.z, ub.w}};

        const unsigned int wq = bw >> (quad * 8);
        unsigned int pk[4];
        #pragma unroll
        for (int m = 0; m < 4; ++m) {
            f32x2 p1 = etq[m] * esv;              // v_pk_mul_f32
            f32x2 p2 = et2q[m] * es2v;            // v_pk_mul_f32
            float w0 = fmaxf(p1[0], p2[0]);
            float w1 = fmaxf(p1[1], p2[1]);
            unsigned int pkm;
            asm("v_cvt_pk_bf16_f32 %0, %1, %2" : "=v"(pkm) : "v"(w0), "v"(w1));
            const int j0 = 2 * m, j1 = 2 * m + 1;
            const unsigned int lo = (unsigned int)((int)(wq << (31 - j0)) >> 31);
            const unsigned int hi = (unsigned int)((int)(wq << (31 - j1)) >> 31);
            pk[m] = pkm & ((lo & 0x0000FFFFu) | (hi & 0xFFFF0000u));
        }
        uint4 bv; bv.x = pk[0]; bv.y = pk[1]; bv.z = pk[2]; bv.w = pk[3];
        bf16x8 bfrag = __builtin_bit_cast(bf16x8, bv);
        apd    = __builtin_amdgcn_mfma_f32_16x16x32_bf16(aones, bfrag, apd, 0, 0, 0);
        acc[0] = __builtin_amdgcn_mfma_f32_16x16x32_bf16(__builtin_bit_cast(bf16x8, av0), bfrag, acc[0], 0, 0, 0);
        acc[1] = __builtin_amdgcn_mfma_f32_16x16x32_bf16(__builtin_bit_cast(bf16x8, av1), bfrag, acc[1], 0, 0, 0);
        acc[2] = __builtin_amdgcn_mfma_f32_16x16x32_bf16(__builtin_bit_cast(bf16x8, av2), bfrag, acc[2], 0, 0, 0);
        acc[3] = __builtin_amdgcn_mfma_f32_16x16x32_bf16(__builtin_bit_cast(bf16x8, av3), bfrag, acc[3], 0, 0, 0);
    }

    // ---- phase 3: combine 4 k-quarters per row-half, denominator, store ----
    __syncthreads();             // all waves done with et tables before overwrite
    if (kq != 0) {
        // slot (rh*3 + kq-1): 6 slots x 64 lanes x 20 floats = 30720 B
        float* cb = smem + ((rh * 3 + (kq - 1)) * 64 + lane) * 20;
        #pragma unroll
        for (int i = 0; i < 4; ++i) ((f32x4*)cb)[i] = acc[i];
        cb[16] = apd[0];
    }
    __syncthreads();
    if (kq == 0) {
        float pd = apd[0];
        #pragma unroll
        for (int q = 0; q < 3; ++q) {
            const float* cb = smem + ((rh * 3 + q) * 64 + lane) * 20;
            #pragma unroll
            for (int i = 0; i < 4; ++i) acc[i] += ((const f32x4*)cb)[i];
            pd += cb[16];
        }
        const float rd = 1.0f / pd;           // ones-MFMA already summed quads
        float4* op = (float4*)(out + head * HT_STRIDE + (i0 + 16 * rh + li) * 64);
        #pragma unroll
        for (int f = 0; f < 4; ++f) {
            f32x4 a = acc[f];
            op[f * 4 + quad] = make_float4(a[0] * rd, a[1] * rd, a[2] * rd, a[3] * rd);
        }
    }
}

extern "C" void kernel_launch(void* const* d_in, const int* in_sizes, int n_in,
                              void* d_out, int out_size, void* d_ws, size_t ws_size,
                              hipStream_t stream) {
    const float* h   = (const float*)d_in[0];  // (1,4096,128) f32
    const int*   adj = (const int*)d_in[1];    // (4096,4096) i32
    const float* W   = (const float*)d_in[2];  // (128,512) f32
    const float* aW  = (const float*)d_in[3];  // (8,128,1) f32
    float* out = (float*)d_out;                // (1,8,4096,64) f32

    // ws layout (6.5 MB): ess(256K) | ets(256K) | abm(2MB) | htT2(4MB)
    char* ws = (char*)d_ws;
    float* ess = (float*)(ws);
    float* ets = (float*)(ws + 262144);
    unsigned int*   abm  = (unsigned int*)(ws + 524288);
    unsigned short* htT2 = (unsigned short*)(ws + 2621440);

    hipLaunchKernelGGL(k_fused, dim3(1024), dim3(256), 0, stream,
                       h, adj, W, aW, ess, ets, htT2, abm);
    hipLaunchKernelGGL(k_attn,  dim3(1024), dim3(512), 0, stream,
                       abm, htT2, ess, ets, out);
}

// Round 11
// 151.135 us; speedup vs baseline: 2.6578x; 1.2233x over previous
//
#include <hip/hip_runtime.h>
#include <stdint.h>

#define HT_STRIDE 262144   // 4096*64 elements per head
#define LOG2E 1.4426950408889634f

typedef __attribute__((ext_vector_type(8))) short bf16x8;
typedef __attribute__((ext_vector_type(4))) float f32x4;
typedef __attribute__((ext_vector_type(2))) float f32x2;

__device__ __forceinline__ unsigned short f2bf(float f) {
    unsigned int u = __float_as_uint(f);
    u += 0x7FFFu + ((u >> 16) & 1u);
    return (unsigned short)(u >> 16);
}

__device__ __forceinline__ float exp2_fast(float e) {
#if __has_builtin(__builtin_amdgcn_exp2f)
    return __builtin_amdgcn_exp2f(e);
#else
    return __expf(e * 0.6931471805599453f);   // expf(ln2*x) == 2^x
#endif
}

// ---------------------------------------------------------------------------
// Kernel 1 (heterogeneous fusion, 1024 blocks x 256 thr, bid&1 interleave):
//  even blocks: adjacency (64 MB, read once at HBM rate) -> 2 MB bitmask
//               abm[s64][c 128][li 16][g 4].
//  odd blocks : linear + prep (ht never touches global). W loads 4-deep
//               prefetched. Emits ess/ets exp tables (max-of-products
//               identity) + bf16 k-tiled htT2.
// ---------------------------------------------------------------------------
__global__ void __launch_bounds__(256) k_fused(const float* __restrict__ h,
                                               const int* __restrict__ adj,
                                               const float* __restrict__ W,
                                               const float* __restrict__ aW,
                                               float* __restrict__ ess,
                                               float* __restrict__ ets,
                                               unsigned short* __restrict__ htT2,
                                               unsigned int* __restrict__ abm) {
    __shared__ unsigned int ldsT[1024];
    __shared__ float hs[8][128];
    __shared__ float ldsA[64][66];
    __shared__ float redS[4][64];
    __shared__ float redT[4][64];
    const int t = threadIdx.x;

    if ((blockIdx.x & 1) == 0) {
        // ---------------- adjmask half ----------------
        const int eid = (int)blockIdx.x >> 1;   // 0..511
        const int lane = t & 63;
        const int w = t >> 6;
        const int sb = eid >> 3;
        const int cq = eid & 7;
        for (int rr = 0; rr < 16; ++rr) {
            const int* arow = adj + (sb * 64 + w * 16 + rr) * 4096 + cq * 512;
            int v[8];
            #pragma unroll
            for (int j = 0; j < 8; ++j) v[j] = arow[j * 64 + lane];
            #pragma unroll
            for (int j = 0; j < 8; ++j) {
                unsigned long long m = __ballot(v[j] > 0);
                if (lane < 2)
                    ldsT[(2 * j + lane) * 64 + rr * 4 + w] = (unsigned int)(m >> (lane * 32));
            }
        }
        __syncthreads();
        ((uint4*)(abm + (sb * 128 + cq * 16) * 64))[t] = ((uint4*)ldsT)[t];
    } else {
        // ---------------- linear + prep half ----------------
        const int bid2 = (int)blockIdx.x >> 1;  // 0..511
        const int n0 = bid2 * 8;            // P-row base (rows of h @ W)
        const int p0 = bid2 * 64;           // flat node base = hd*4096 + m0
        const int hd = p0 >> 12;
        const int m0 = p0 & 4095;

        // stage 8 h-rows (4 KB), coalesced
        {
            float4 v = ((const float4*)(h + n0 * 128))[t];
            int e = t * 4;
            int r = e >> 7, f = e & 127;
            hs[r][f + 0] = v.x; hs[r][f + 1] = v.y;
            hs[r][f + 2] = v.z; hs[r][f + 3] = v.w;
        }
        __syncthreads();

        // 8x512 P-tile: thread t owns cols (2t, 2t+1) for all 8 rows.
        // W loads 4-deep prefetched: issue chunk fb+1 before computing fb.
        float acc0[8], acc1[8];
        #pragma unroll
        for (int r = 0; r < 8; ++r) { acc0[r] = 0.f; acc1[r] = 0.f; }
        const float2* Wf = (const float2*)W;
        float2 wpb[4];
        #pragma unroll
        for (int j = 0; j < 4; ++j) wpb[j] = Wf[j * 256 + t];
        for (int fb = 0; fb < 32; ++fb) {
            const int fn = ((fb + 1) & 31) * 4;      // fb=31 wraps (harmless)
            float2 wn[4];
            #pragma unroll
            for (int j = 0; j < 4; ++j) wn[j] = Wf[(fn + j) * 256 + t];
            #pragma unroll
            for (int j = 0; j < 4; ++j) {
                const int f = fb * 4 + j;
                #pragma unroll
                for (int r = 0; r < 8; ++r) {
                    float hv = hs[r][f];
                    acc0[r] = fmaf(hv, wpb[j].x, acc0[r]);
                    acc1[r] = fmaf(hv, wpb[j].y, acc1[r]);
                }
            }
            #pragma unroll
            for (int j = 0; j < 4; ++j) wpb[j] = wn[j];
        }
        // scatter into node-major tile: node = 8r + (2t)>>6, o = (2t)&63
        {
            const int ns = t >> 5;
            const int o = (2 * t) & 63;
            #pragma unroll
            for (int r = 0; r < 8; ++r) {
                *(float2*)&ldsA[r * 8 + ns][o] = make_float2(acc0[r], acc1[r]);
            }
        }
        __syncthreads();

        // src/tgt projections
        {
            const int r = t & 63, og = t >> 6;
            float sdot = 0.f, gdot = 0.f;
            #pragma unroll
            for (int k = 0; k < 16; ++k) {
                int o = og * 16 + k;
                float hv = ldsA[r][o];
                sdot = fmaf(hv, aW[hd * 128 + o], sdot);
                gdot = fmaf(hv, aW[hd * 128 + 64 + o], gdot);
            }
            redS[og][r] = sdot; redT[og][r] = gdot;
        }
        __syncthreads();
        if (t < 64) {
            float sp = (redS[0][t] + redS[1][t] + redS[2][t] + redS[3][t]) * LOG2E;
            ess[hd * 8192 + m0 + t]        = exp2_fast(sp);
            ess[hd * 8192 + 4096 + m0 + t] = exp2_fast(0.2f * sp);
        } else if (t < 128) {
            int r = t - 64;
            float tv = (redT[0][r] + redT[1][r] + redT[2][r] + redT[3][r]) * LOG2E;
            ets[hd * 8192 + m0 + r]        = exp2_fast(tv);
            ets[hd * 8192 + 4096 + m0 + r] = exp2_fast(0.2f * tv);
        }

        // bf16 k-tiled transpose out (reads ldsA, stable since last barrier)
        unsigned short* d = htT2 + (hd * 128 + (m0 >> 5)) * 2048;
        #pragma unroll
        for (int i = 0; i < 16; ++i) {
            int id = t + 256 * i;
            int mi = id & 31, o = (id >> 5) & 63, ct = id >> 11;
            d[ct * 2048 + o * 32 + mi] = f2bf(ldsA[mi + 32 * ct][o]);
        }
    }
}

// ---------------------------------------------------------------------------
// Kernel 2 v13: LDS-staged A-tiles — kill the vmem-instruction wall.
// Model (R3-R10 fit): k_attn dur ~= (L1-missing vmem instrs per CU) x ~45cy
// at >=4 waves/SIMD. v8: 2560 instr/CU -> 45us. v12: 5120 -> 82us.
// v13: block = 64 rows x FULL k. 512 thr, 8 waves = 4 row-groups (g) x
// 2 k-halves (kh). Each 4KB c-tile loaded ONCE per block (reg-staged,
// issue-early/write-late, double-buffered, 1 barrier/iter — m97 pattern),
// consumed by 4 waves via conflict-free ds_read_b128.
// Per-CU vmem: 2 blocks x 128 tiles x 4 = 1024 staging instrs (~19us)
// + 1-line bitword reads. VALU floor ~12us at 4 waves/SIMD (2 blocks/CU,
// staggered barriers). Combine: ONE stage (kh=1 -> kh=0).
// NO __launch_bounds__ min-waves (R8/R9: cap below arch+acc demand
// spills accumulators -> 100x WRITE_SIZE).
// LDS 48KB: [et 16K | et2 16K | A-bufs 2kh x 2par x 4K]; combine unions
// into the table region after the final barrier.
// ---------------------------------------------------------------------------
__global__ void __launch_bounds__(512) k_attn(const unsigned int* __restrict__ abm,
                                              const unsigned short* __restrict__ htT2,
                                              const float* __restrict__ ess,
                                              const float* __restrict__ ets,
                                              float* __restrict__ out) {
    __shared__ __align__(16) float smem[12288];   // 49152 B

    const int t = threadIdx.x;
    const int wv = t >> 6;                   // 0..7
    const int kh = wv >> 2;                  // k-half 0..1
    const int g  = wv & 3;                   // row-group 0..3
    const int lane = t & 63;
    const int li = lane & 15;
    const int quad = lane >> 4;
    const int head = blockIdx.x & 7;         // == XCD -> L2-pinned htT2 slice
    const int s64 = blockIdx.x >> 3;         // 0..63
    const int i0 = s64 * 64;

    // stage SoA et/et2 head-slice (32 KB)
    {
        const float4* esrc = (const float4*)(ets + head * 8192);
        float4* edst = (float4*)smem;
        #pragma unroll
        for (int i = 0; i < 4; ++i) edst[t + 512 * i] = esrc[t + 512 * i];
    }

    // per-row constants (this wave's 16 rows)
    const float e1 = ess[head * 8192 + i0 + 16 * g + li];
    const float e2 = ess[head * 8192 + 4096 + i0 + 16 * g + li];
    const f32x2 esv  = (f32x2){e1, e1};
    const f32x2 es2v = (f32x2){e2, e2};

    f32x4 acc[4];
    #pragma unroll
    for (int i = 0; i < 4; ++i) acc[i] = (f32x4){0.f, 0.f, 0.f, 0.f};
    f32x4 apd = (f32x4){0.f, 0.f, 0.f, 0.f};

    const uint4 onesw = {0x3F803F80u, 0x3F803F80u, 0x3F803F80u, 0x3F803F80u};
    const bf16x8 aones = __builtin_bit_cast(bf16x8, onesw);

    // ---- A-tile staging setup ----
    // tile (head, c) = 4KB contiguous at htT2 + (head*128 + c)*2048 shorts.
    // thread t stages 16B slot sc of the tile for k-half skh (self-aligned:
    // waves 0-3 are kh=0 and t<256 -> skh=0).
    const int sc  = t & 255;
    const int skh = t >> 8;
    const uint4* gtile = (const uint4*)(htT2 + head * HT_STRIDE);
    float* bufb = smem + 8192;               // 4 buffers x 1024 floats

    uint4 stg0 = gtile[(skh * 64 + 0) * 256 + sc];
    uint4 stgN = gtile[(skh * 64 + 1) * 256 + sc];
    ((uint4*)(bufb + (skh * 2 + 0) * 1024))[sc] = stg0;

    const unsigned int* bmp = abm + s64 * 8192 + g;

    __syncthreads();

    #pragma unroll 1
    for (int ci = 0; ci < 64; ++ci) {
        const int c = kh * 64 + ci;
        // prefetch tile ci+2 (clamped; issues early, hides under compute)
        const int cp = (ci < 62) ? (ci + 2) : 63;
        uint4 stgF = gtile[(skh * 64 + cp) * 256 + sc];

        // ---- compute tile ci from LDS ----
        const uint4* abuf = (const uint4*)(bufb + (kh * 2 + (ci & 1)) * 1024);
        uint4 av0 = abuf[  0 + li * 4 + quad];
        uint4 av1 = abuf[ 64 + li * 4 + quad];
        uint4 av2 = abuf[128 + li * 4 + quad];
        uint4 av3 = abuf[192 + li * 4 + quad];
        const unsigned int bw = bmp[c * 64 + li * 4];   // L2-resident bitword

        const float4* etp  = (const float4*)(smem + c * 32 + quad * 8);
        const float4* et2p = (const float4*)(smem + 4096 + c * 32 + quad * 8);
        float4 ta = etp[0],  tb = etp[1];
        float4 ua = et2p[0], ub = et2p[1];
        const f32x2 etq[4]  = {(f32x2){ta.x, ta.y}, (f32x2){ta.z, ta.w},
                               (f32x2){tb.x, tb.y}, (f32x2){tb.z, tb.w}};
        const f32x2 et2q[4] = {(f32x2){ua.x, ua.y}, (f32x2){ua.z, ua.w},
                               (f32x2){ub.x, ub.y}, (f32x2){ub.z, ub.w}};

        const unsigned int wq = bw >> (quad * 8);
        unsigned int pk[4];
        #pragma unroll
        for (int m = 0; m < 4; ++m) {
            f32x2 p1 = etq[m] * esv;              // v_pk_mul_f32
            f32x2 p2 = et2q[m] * es2v;            // v_pk_mul_f32
            float w0 = fmaxf(p1[0], p2[0]);
            float w1 = fmaxf(p1[1], p2[1]);
            unsigned int pkm;
            asm("v_cvt_pk_bf16_f32 %0, %1, %2" : "=v"(pkm) : "v"(w0), "v"(w1));
            const int j0 = 2 * m, j1 = 2 * m + 1;
            const unsigned int lo = (unsigned int)((int)(wq << (31 - j0)) >> 31);
            const unsigned int hi = (unsigned int)((int)(wq << (31 - j1)) >> 31);
            pk[m] = pkm & ((lo & 0x0000FFFFu) | (hi & 0xFFFF0000u));
        }
        uint4 bv; bv.x = pk[0]; bv.y = pk[1]; bv.z = pk[2]; bv.w = pk[3];
        bf16x8 bfrag = __builtin_bit_cast(bf16x8, bv);
        apd    = __builtin_amdgcn_mfma_f32_16x16x32_bf16(aones, bfrag, apd, 0, 0, 0);
        acc[0] = __builtin_amdgcn_mfma_f32_16x16x32_bf16(__builtin_bit_cast(bf16x8, av0), bfrag, acc[0], 0, 0, 0);
        acc[1] = __builtin_amdgcn_mfma_f32_16x16x32_bf16(__builtin_bit_cast(bf16x8, av1), bfrag, acc[1], 0, 0, 0);
        acc[2] = __builtin_amdgcn_mfma_f32_16x16x32_bf16(__builtin_bit_cast(bf16x8, av2), bfrag, acc[2], 0, 0, 0);
        acc[3] = __builtin_amdgcn_mfma_f32_16x16x32_bf16(__builtin_bit_cast(bf16x8, av3), bfrag, acc[3], 0, 0, 0);

        // ---- write tile ci+1 into the idle buffer (write-late), barrier ----
        ((uint4*)(bufb + (skh * 2 + ((ci + 1) & 1)) * 1024))[sc] = stgN;
        __syncthreads();
        stgN = stgF;
    }

    // ---- combine the 2 k-halves (union over table region), store ----
    if (kh == 1) {
        float* cb = smem + (g * 64 + lane) * 20;   // 4x64x20 floats = 20 KB
        #pragma unroll
        for (int i = 0; i < 4; ++i) ((f32x4*)cb)[i] = acc[i];
        cb[16] = apd[0];
    }
    __syncthreads();
    if (kh == 0) {
        const float* cb = smem + (g * 64 + lane) * 20;
        #pragma unroll
        for (int i = 0; i < 4; ++i) acc[i] += ((const f32x4*)cb)[i];
        const float pd = apd[0] + cb[16];
        const float rd = 1.0f / pd;               // ones-MFMA already summed quads
        float4* op = (float4*)(out + head * HT_STRIDE + (i0 + 16 * g + li) * 64);
        #pragma unroll
        for (int f = 0; f < 4; ++f) {
            f32x4 a = acc[f];
            op[f * 4 + quad] = make_float4(a[0] * rd, a[1] * rd, a[2] * rd, a[3] * rd);
        }
    }
}

extern "C" void kernel_launch(void* const* d_in, const int* in_sizes, int n_in,
                              void* d_out, int out_size, void* d_ws, size_t ws_size,
                              hipStream_t stream) {
    const float* h   = (const float*)d_in[0];  // (1,4096,128) f32
    const int*   adj = (const int*)d_in[1];    // (4096,4096) i32
    const float* W   = (const float*)d_in[2];  // (128,512) f32
    const float* aW  = (const float*)d_in[3];  // (8,128,1) f32
    float* out = (float*)d_out;                // (1,8,4096,64) f32

    // ws layout (6.5 MB): ess(256K) | ets(256K) | abm(2MB) | htT2(4MB)
    char* ws = (char*)d_ws;
    float* ess = (float*)(ws);
    float* ets = (float*)(ws + 262144);
    unsigned int*   abm  = (unsigned int*)(ws + 524288);
    unsigned short* htT2 = (unsigned short*)(ws + 2621440);

    hipLaunchKernelGGL(k_fused, dim3(1024), dim3(256), 0, stream,
                       h, adj, W, aW, ess, ets, htT2, abm);
    hipLaunchKernelGGL(k_attn,  dim3(512),  dim3(512), 0, stream,
                       abm, htT2, ess, ets, out);
}